// Round 7
// baseline (235.686 us; speedup 1.0000x reference)
//
#include <hip/hip_runtime.h>
#include <hip/hip_bf16.h>
#include <math.h>

#define NN 8192
#define QSCALE (0.125f * 1.44269504088896f)   // fold 0.125 and log2(e) into Q
#define OSZ (8192*64)
#define NSL 8                                  // pass2 j-slices

typedef __attribute__((ext_vector_type(8))) short short8;
typedef __attribute__((ext_vector_type(16))) float f32x16;

union W4 { unsigned u[4]; short8 v; };

__device__ inline unsigned short f2bf(float x) {
  union { float f; unsigned u; } t; t.f = x;
  unsigned r = t.u + 0x7fffu + ((t.u >> 16) & 1u);
  return (unsigned short)(r >> 16);
}
__device__ inline unsigned cvtpk(float lo, float hi) {
  unsigned r;
  asm("v_cvt_pk_bf16_f32 %0, %1, %2" : "=v"(r) : "v"(lo), "v"(hi));
  return r;
}
__device__ inline float fexp2(float x) {
  float r;
  asm("v_exp_f32 %0, %1" : "=v"(r) : "v"(x));
  return r;
}

// ---------------------------------------------------------------------------
// Kernel 1: Q/K/V/H pre-pack.
//  QP[c8][i][e] = Q[i][c8*8+e]*QSCALE ; KP same for K
//  VP[j8][d][e] = V[j8*8+e][d] ; HP same for H
// ---------------------------------------------------------------------------
__global__ __launch_bounds__(256) void qkv_kernel(
    const float* __restrict__ X, const float* __restrict__ H,
    const float* __restrict__ Qw, const float* __restrict__ Qb,
    const float* __restrict__ Kw, const float* __restrict__ Kb,
    const float* __restrict__ Vw, const float* __restrict__ Vb,
    const float* __restrict__ bng, const float* __restrict__ bnb,
    const float* __restrict__ bnm, const float* __restrict__ bnv,
    unsigned short* __restrict__ QP, unsigned short* __restrict__ KP,
    unsigned short* __restrict__ VP, unsigned short* __restrict__ HP)
{
  int wid = (blockIdx.x * blockDim.x + threadIdx.x) >> 6; // 0..2047
  int d = threadIdx.x & 63;
  float4 w[16];

  for (int fq = 0; fq < 16; fq++) w[fq] = *(const float4*)(Qw + d*64 + fq*4);
  for (int rr = 0; rr < 4; rr++) {
    int r = wid*4 + rr;
    float a = Qb[d];
    for (int fq = 0; fq < 16; fq++) {
      float4 xv = *(const float4*)(X + r*64 + fq*4);
      a += w[fq].x*xv.x + w[fq].y*xv.y + w[fq].z*xv.z + w[fq].w*xv.w;
    }
    float s = a;
    for (int off = 32; off; off >>= 1) s += __shfl_xor(s, off);
    float mean = s * (1.f/64.f);
    float c = a - mean;
    float s2 = c*c;
    for (int off = 32; off; off >>= 1) s2 += __shfl_xor(s2, off);
    float q = c * rsqrtf(s2*(1.f/64.f) + 1e-5f);
    QP[(d>>3)*65536 + r*8 + (d&7)] = f2bf(q * QSCALE);
  }
  for (int fq = 0; fq < 16; fq++) w[fq] = *(const float4*)(Kw + d*64 + fq*4);
  for (int rr = 0; rr < 4; rr++) {
    int r = wid*4 + rr;
    float a = Kb[d];
    for (int fq = 0; fq < 16; fq++) {
      float4 hv = *(const float4*)(H + r*64 + fq*4);
      a += w[fq].x*hv.x + w[fq].y*hv.y + w[fq].z*hv.z + w[fq].w*hv.w;
    }
    float s = a;
    for (int off = 32; off; off >>= 1) s += __shfl_xor(s, off);
    float mean = s * (1.f/64.f);
    float c = a - mean;
    float s2 = c*c;
    for (int off = 32; off; off >>= 1) s2 += __shfl_xor(s2, off);
    float k = c * rsqrtf(s2*(1.f/64.f) + 1e-5f);
    KP[(d>>3)*65536 + r*8 + (d&7)] = f2bf(k);
  }
  for (int fq = 0; fq < 16; fq++) w[fq] = *(const float4*)(Vw + d*64 + fq*4);
  float bscale = rsqrtf(bnv[d] + 1e-5f) * bng[d];
  for (int rr = 0; rr < 4; rr++) {
    int r = wid*4 + rr;
    float a = Vb[d];
    for (int fq = 0; fq < 16; fq++) {
      float4 hv = *(const float4*)(H + r*64 + fq*4);
      a += w[fq].x*hv.x + w[fq].y*hv.y + w[fq].z*hv.z + w[fq].w*hv.w;
    }
    float v = (a - bnm[d]) * bscale + bnb[d];
    VP[(r>>3)*512 + d*8 + (r&7)] = f2bf(v);
    HP[(r>>3)*512 + d*8 + (r&7)] = f2bf(H[r*64 + d]);
  }
}

// ---------------------------------------------------------------------------
// pass 1 (lean): per-column sums of exp2(s*M). No LDS, no MT4, no barrier.
// Pure 256 MB nontemporal read stream + L2-resident QP/KP fragments.
// ---------------------------------------------------------------------------
__global__ __launch_bounds__(256) void pass1_kernel(
    const float* __restrict__ M, const unsigned short* __restrict__ QP,
    const unsigned short* __restrict__ KP, float* __restrict__ pd)
{
  int tid = threadIdx.x;
  int wj = (blockIdx.x * blockDim.x + tid) >> 6;  // 0..8191
  int lane = tid & 63;
  int l31 = lane & 31, h = lane >> 5;
  int jb = wj & 255, slice = wj >> 8;             // 256 jb x 32 slices
  int j = jb*32 + l31;

  short8 kb[4];
  for (int m = 0; m < 4; m++)
    kb[m] = *(const short8*)(KP + (2*m + h)*65536 + j*8);

  float Mv[16];
  {
    int i0 = slice*8*32;
#pragma unroll
    for (int r = 0; r < 16; r++) {
      int ir = (r&3) + 8*(r>>2) + 4*h;
      Mv[r] = __builtin_nontemporal_load(M + (size_t)(i0 + ir)*NN + j);
    }
  }

  float d0 = 0.f, d1 = 0.f, d2 = 0.f, d3 = 0.f;
  for (int t = 0; t < 8; t++) {
    int i0 = (slice*8 + t) * 32;
    float Mn[16];
    if (t < 7) {
      int i1 = i0 + 32;
#pragma unroll
      for (int r = 0; r < 16; r++) {
        int ir = (r&3) + 8*(r>>2) + 4*h;
        Mn[r] = __builtin_nontemporal_load(M + (size_t)(i1 + ir)*NN + j);
      }
    }

    f32x16 acc;
    for (int r = 0; r < 16; r++) acc[r] = 0.f;
    for (int m = 0; m < 4; m++) {
      short8 qa = *(const short8*)(QP + (2*m + h)*65536 + (size_t)(i0 + l31)*8);
      acc = __builtin_amdgcn_mfma_f32_32x32x16_bf16(qa, kb[m], acc, 0, 0, 0);
    }

    d0 += fexp2(acc[0]*Mv[0]) + fexp2(acc[4]*Mv[4]) + fexp2(acc[8]*Mv[8])   + fexp2(acc[12]*Mv[12]);
    d1 += fexp2(acc[1]*Mv[1]) + fexp2(acc[5]*Mv[5]) + fexp2(acc[9]*Mv[9])   + fexp2(acc[13]*Mv[13]);
    d2 += fexp2(acc[2]*Mv[2]) + fexp2(acc[6]*Mv[6]) + fexp2(acc[10]*Mv[10]) + fexp2(acc[14]*Mv[14]);
    d3 += fexp2(acc[3]*Mv[3]) + fexp2(acc[7]*Mv[7]) + fexp2(acc[11]*Mv[11]) + fexp2(acc[15]*Mv[15]);

    if (t < 7) {
#pragma unroll
      for (int r = 0; r < 16; r++) Mv[r] = Mn[r];
    }
  }
  float drun = (d0 + d1) + (d2 + d3);
  drun += __shfl_xor(drun, 32);
  if (lane < 32) pd[(size_t)slice*NN + j] = drun;
}

// ---------------------------------------------------------------------------
// combine: cc[j] = log2(10 * D_j)
// ---------------------------------------------------------------------------
__global__ __launch_bounds__(256) void combine_kernel(
    const float* __restrict__ pd, float* __restrict__ colcc)
{
  int j = blockIdx.x * blockDim.x + threadIdx.x;
  float Dv = 0.f;
  for (int s = 0; s < 32; s++) Dv += pd[(size_t)s*NN + j];
  colcc[j] = log2f(Dv * 10.f);
}

// ---------------------------------------------------------------------------
// pass 2: partial out = alpha*A@V + M@H per 1024-col j-slice. M re-read
// directly (coalesced 256B-granule staging into LDS, stride-66 pad), Mv via
// conflict-free ds_read_b64, f32 M in exp; M@H A-frags built from Mv via
// cvtpk + permlane32_swap (same cross pattern as the P path).
// Grid = 128 iblk x 8 slices; WG = 4 waves (iq = wid&1, dh = wid>>1).
// ---------------------------------------------------------------------------
#define MST 66   // 64 + 2 pad floats

__global__ __launch_bounds__(256) void pass2_kernel(
    const float* __restrict__ M, const unsigned short* __restrict__ QP,
    const unsigned short* __restrict__ KP, const unsigned short* __restrict__ VP,
    const unsigned short* __restrict__ HP, const float* __restrict__ colcc,
    float* __restrict__ opart)
{
  __shared__ __align__(16) float mt[2][64*MST];
  __shared__ __align__(16) float cls[1024];

  int iblk = blockIdx.x >> 3, slice = blockIdx.x & 7;
  int i0 = iblk * 64;
  int tid = threadIdx.x;
  int lane = tid & 63, wid = tid >> 6;
  int l31 = lane & 31, h = lane >> 5;
  int iq = wid & 1, dh = wid >> 1;
  int row = iq*32 + l31;
  int i_g = i0 + row;

  short8 qb[4];
  for (int m = 0; m < 4; m++)
    qb[m] = *(const short8*)(QP + (2*m + h)*65536 + (size_t)i_g*8);

#pragma unroll
  for (int k = 0; k < 4; k++)
    cls[tid + k*256] = colcc[slice*1024 + k*256 + tid];

  // staging map: idx = q*256+tid -> row idx>>4 (0..63), col (idx&15)*4
  const float* msrc = M + (size_t)i0*NN + slice*1024;

  // prologue: stage tile 0
#pragma unroll
  for (int q = 0; q < 4; q++) {
    int idx = q*256 + tid, r = idx >> 4, c = (idx & 15) * 4;
    float4 v = *(const float4*)(msrc + (size_t)r*NN + c);
    float* dst = &mt[0][r*MST + c];
    *(float2*)(dst)     = make_float2(v.x, v.y);
    *(float2*)(dst + 2) = make_float2(v.z, v.w);
  }
  __syncthreads();

  f32x16 oacc;
  for (int r = 0; r < 16; r++) oacc[r] = 0.f;

  for (int tm = 0; tm < 16; tm++) {
    // stage tile tm+1 into the other buffer
    if (tm < 15) {
      const float* src = msrc + (tm+1)*64;
      float* dstb = mt[(tm+1) & 1];
#pragma unroll
      for (int q = 0; q < 4; q++) {
        int idx = q*256 + tid, r = idx >> 4, c = (idx & 15) * 4;
        float4 v = *(const float4*)(src + (size_t)r*NN + c);
        float* dst = &dstb[r*MST + c];
        *(float2*)(dst)     = make_float2(v.x, v.y);
        *(float2*)(dst + 2) = make_float2(v.z, v.w);
      }
    }
    const float* mb = mt[tm & 1];

#pragma unroll
    for (int ti = 0; ti < 2; ti++) {
      int jt = slice*1024 + tm*64 + ti*32;
      int jloc = tm*64 + ti*32;

      // ---- KP frags + QK^T (swapped: lane = i, regs = j) ----
      f32x16 sacc;
      for (int r = 0; r < 16; r++) sacc[r] = 0.f;
      for (int m = 0; m < 4; m++) {
        short8 ka = *(const short8*)(KP + (2*m + h)*65536 + (size_t)(jt + l31)*8);
        sacc = __builtin_amdgcn_mfma_f32_32x32x16_bf16(ka, qb[m], sacc, 0, 0, 0);
      }

      // ---- Mv from LDS: 8 x b64, conflict-free ----
      float2 mv2[8];
#pragma unroll
      for (int q = 0; q < 4; q++) {
        const float* rb = &mb[row*MST + ti*32 + 8*q + 4*h];
        mv2[2*q]   = *(const float2*)(rb);
        mv2[2*q+1] = *(const float2*)(rb + 2);
      }

      // ---- p = exp2(s*M - cc) (f32 M) ----
      float p[16];
#pragma unroll
      for (int q = 0; q < 4; q++) {
        float4 cc = *(const float4*)(&cls[jloc + 8*q + 4*h]);
        p[4*q+0] = fexp2(fmaf(sacc[4*q+0], mv2[2*q].x,   -cc.x));
        p[4*q+1] = fexp2(fmaf(sacc[4*q+1], mv2[2*q].y,   -cc.y));
        p[4*q+2] = fexp2(fmaf(sacc[4*q+2], mv2[2*q+1].x, -cc.z));
        p[4*q+3] = fexp2(fmaf(sacc[4*q+3], mv2[2*q+1].y, -cc.w));
      }

      // ---- pack P and M to bf16 words ----
      unsigned pu[8], mw[8];
#pragma unroll
      for (int k = 0; k < 8; k++) pu[k] = cvtpk(p[2*k], p[2*k+1]);
#pragma unroll
      for (int k = 0; k < 8; k++) mw[k] = cvtpk(mv2[k].x, mv2[k].y);

      // ---- half-swaps -> A-frag words (same cross pattern both) ----
      asm volatile("v_permlane32_swap_b32 %0, %1" : "+v"(pu[0]), "+v"(pu[2]));
      asm volatile("v_permlane32_swap_b32 %0, %1" : "+v"(pu[1]), "+v"(pu[3]));
      asm volatile("v_permlane32_swap_b32 %0, %1" : "+v"(pu[4]), "+v"(pu[6]));
      asm volatile("v_permlane32_swap_b32 %0, %1" : "+v"(pu[5]), "+v"(pu[7]));
      asm volatile("v_permlane32_swap_b32 %0, %1" : "+v"(mw[0]), "+v"(mw[2]));
      asm volatile("v_permlane32_swap_b32 %0, %1" : "+v"(mw[1]), "+v"(mw[3]));
      asm volatile("v_permlane32_swap_b32 %0, %1" : "+v"(mw[4]), "+v"(mw[6]));
      asm volatile("v_permlane32_swap_b32 %0, %1" : "+v"(mw[5]), "+v"(mw[7]));

      W4 PA0, PA1, MA0, MA1;
      PA0.u[0] = pu[0]; PA0.u[1] = pu[1]; PA0.u[2] = pu[2]; PA0.u[3] = pu[3];
      PA1.u[0] = pu[4]; PA1.u[1] = pu[5]; PA1.u[2] = pu[6]; PA1.u[3] = pu[7];
      MA0.u[0] = mw[0]; MA0.u[1] = mw[1]; MA0.u[2] = mw[2]; MA0.u[3] = mw[3];
      MA1.u[0] = mw[4]; MA1.u[1] = mw[5]; MA1.u[2] = mw[6]; MA1.u[3] = mw[7];

      // ---- V/H B-frags (L2-resident) ----
      int j8 = jt >> 3;
      const unsigned short* vbase = VP + (size_t)j8*512 + (dh*32 + l31)*8;
      const unsigned short* hbase = HP + (size_t)j8*512 + (dh*32 + l31)*8;
      short8 vb1 = *(const short8*)(vbase + h*512);
      short8 vb2 = *(const short8*)(vbase + (2 + h)*512);
      short8 hb1 = *(const short8*)(hbase + h*512);
      short8 hb2 = *(const short8*)(hbase + (2 + h)*512);

      oacc = __builtin_amdgcn_mfma_f32_32x32x16_bf16(PA0.v, vb1, oacc, 0, 0, 0);
      oacc = __builtin_amdgcn_mfma_f32_32x32x16_bf16(PA1.v, vb2, oacc, 0, 0, 0);
      oacc = __builtin_amdgcn_mfma_f32_32x32x16_bf16(MA0.v, hb1, oacc, 0, 0, 0);
      oacc = __builtin_amdgcn_mfma_f32_32x32x16_bf16(MA1.v, hb2, oacc, 0, 0, 0);
    }
    __syncthreads();
  }

  float* obase = opart + (size_t)slice*OSZ;
#pragma unroll
  for (int r = 0; r < 16; r++) {
    int orow = i0 + iq*32 + (r&3) + 8*(r>>2) + 4*h;
    int ocol = dh*32 + l31;
    obase[(size_t)orow*64 + ocol] = oacc[r];
  }
}

// ---------------------------------------------------------------------------
// reduce: out = sum over NSL slices of opart  (float4, fully coalesced)
// ---------------------------------------------------------------------------
__global__ __launch_bounds__(256) void reduce_kernel(
    const float* __restrict__ opart, float* __restrict__ out)
{
  int e4 = blockIdx.x * blockDim.x + threadIdx.x;   // 0..131071
  const float4* p = (const float4*)opart;
  float4 a = p[e4];
#pragma unroll
  for (int s = 1; s < NSL; s++) {
    float4 b = p[(size_t)s*(OSZ/4) + e4];
    a.x += b.x; a.y += b.y; a.z += b.z; a.w += b.w;
  }
  ((float4*)out)[e4] = a;
}

// ---------------------------------------------------------------------------
extern "C" void kernel_launch(void* const* d_in, const int* in_sizes, int n_in,
                              void* d_out, int out_size, void* d_ws, size_t ws_size,
                              hipStream_t stream) {
  const float* X   = (const float*)d_in[0];
  const float* H   = (const float*)d_in[1];
  const float* M   = (const float*)d_in[2];
  const float* Qw  = (const float*)d_in[3];
  const float* Qb  = (const float*)d_in[4];
  const float* Kw  = (const float*)d_in[5];
  const float* Kb  = (const float*)d_in[6];
  const float* Vw  = (const float*)d_in[7];
  const float* Vb  = (const float*)d_in[8];
  const float* bng = (const float*)d_in[9];
  const float* bnb = (const float*)d_in[10];
  const float* bnm = (const float*)d_in[11];
  const float* bnv = (const float*)d_in[12];
  float* out = (float*)d_out;

  char* ws = (char*)d_ws;
  const size_t MB = 1024*1024;
  unsigned short* QP  = (unsigned short*)(ws);           // 1 MB
  unsigned short* KP  = (unsigned short*)(ws + 1*MB);
  unsigned short* VP  = (unsigned short*)(ws + 2*MB);
  unsigned short* HP  = (unsigned short*)(ws + 3*MB);
  float* pd           = (float*)(ws + 4*MB);             // 1 MB
  float* colcc        = (float*)(ws + 5*MB);             // 32 KB
  float* opart        = (float*)(ws + 6*MB);             // 16 MB

  qkv_kernel<<<512, 256, 0, stream>>>(X, H, Qw, Qb, Kw, Kb, Vw, Vb,
                                      bng, bnb, bnm, bnv, QP, KP, VP, HP);
  pass1_kernel<<<2048, 256, 0, stream>>>(M, QP, KP, pd);
  combine_kernel<<<32, 256, 0, stream>>>(pd, colcc);
  pass2_kernel<<<1024, 256, 0, stream>>>(M, QP, KP, VP, HP, colcc, opart);
  reduce_kernel<<<512, 256, 0, stream>>>(opart, out);
}

// Round 8
// 177.883 us; speedup vs baseline: 1.3249x; 1.3249x over previous
//
#include <hip/hip_runtime.h>
#include <hip/hip_bf16.h>
#include <math.h>

#define NN 8192
#define QSCALE (0.125f * 1.44269504088896f)   // fold 0.125 and log2(e) into Q
#define OSZ (8192*64)
#define NSL 8                                  // pass2 j-slices

typedef __attribute__((ext_vector_type(8))) short short8;
typedef __attribute__((ext_vector_type(16))) float f32x16;
typedef __attribute__((ext_vector_type(4))) float f32x4;

union W4 { unsigned u[4]; short8 v; };

__device__ inline unsigned short f2bf(float x) {
  union { float f; unsigned u; } t; t.f = x;
  unsigned r = t.u + 0x7fffu + ((t.u >> 16) & 1u);
  return (unsigned short)(r >> 16);
}
__device__ inline unsigned cvtpk(float lo, float hi) {
  unsigned r;
  asm("v_cvt_pk_bf16_f32 %0, %1, %2" : "=v"(r) : "v"(lo), "v"(hi));
  return r;
}
__device__ inline float fexp2(float x) {
  float r;
  asm("v_exp_f32 %0, %1" : "=v"(r) : "v"(x));
  return r;
}
__device__ inline f32x4 ntload4(const float* p) {
  return __builtin_nontemporal_load((const f32x4*)p);
}

// ---------------------------------------------------------------------------
// Kernel 1: Q/K/V/H pre-pack.
//  QP[c8][i][e] = Q[i][c8*8+e]*QSCALE ; KP same for K
//  VP[j8][d][e] = V[j8*8+e][d] ; HP same for H
// ---------------------------------------------------------------------------
__global__ __launch_bounds__(256) void qkv_kernel(
    const float* __restrict__ X, const float* __restrict__ H,
    const float* __restrict__ Qw, const float* __restrict__ Qb,
    const float* __restrict__ Kw, const float* __restrict__ Kb,
    const float* __restrict__ Vw, const float* __restrict__ Vb,
    const float* __restrict__ bng, const float* __restrict__ bnb,
    const float* __restrict__ bnm, const float* __restrict__ bnv,
    unsigned short* __restrict__ QP, unsigned short* __restrict__ KP,
    unsigned short* __restrict__ VP, unsigned short* __restrict__ HP)
{
  int wid = (blockIdx.x * blockDim.x + threadIdx.x) >> 6; // 0..2047
  int d = threadIdx.x & 63;
  float4 w[16];

  for (int fq = 0; fq < 16; fq++) w[fq] = *(const float4*)(Qw + d*64 + fq*4);
  for (int rr = 0; rr < 4; rr++) {
    int r = wid*4 + rr;
    float a = Qb[d];
    for (int fq = 0; fq < 16; fq++) {
      float4 xv = *(const float4*)(X + r*64 + fq*4);
      a += w[fq].x*xv.x + w[fq].y*xv.y + w[fq].z*xv.z + w[fq].w*xv.w;
    }
    float s = a;
    for (int off = 32; off; off >>= 1) s += __shfl_xor(s, off);
    float mean = s * (1.f/64.f);
    float c = a - mean;
    float s2 = c*c;
    for (int off = 32; off; off >>= 1) s2 += __shfl_xor(s2, off);
    float q = c * rsqrtf(s2*(1.f/64.f) + 1e-5f);
    QP[(d>>3)*65536 + r*8 + (d&7)] = f2bf(q * QSCALE);
  }
  for (int fq = 0; fq < 16; fq++) w[fq] = *(const float4*)(Kw + d*64 + fq*4);
  for (int rr = 0; rr < 4; rr++) {
    int r = wid*4 + rr;
    float a = Kb[d];
    for (int fq = 0; fq < 16; fq++) {
      float4 hv = *(const float4*)(H + r*64 + fq*4);
      a += w[fq].x*hv.x + w[fq].y*hv.y + w[fq].z*hv.z + w[fq].w*hv.w;
    }
    float s = a;
    for (int off = 32; off; off >>= 1) s += __shfl_xor(s, off);
    float mean = s * (1.f/64.f);
    float c = a - mean;
    float s2 = c*c;
    for (int off = 32; off; off >>= 1) s2 += __shfl_xor(s2, off);
    float k = c * rsqrtf(s2*(1.f/64.f) + 1e-5f);
    KP[(d>>3)*65536 + r*8 + (d&7)] = f2bf(k);
  }
  for (int fq = 0; fq < 16; fq++) w[fq] = *(const float4*)(Vw + d*64 + fq*4);
  float bscale = rsqrtf(bnv[d] + 1e-5f) * bng[d];
  for (int rr = 0; rr < 4; rr++) {
    int r = wid*4 + rr;
    float a = Vb[d];
    for (int fq = 0; fq < 16; fq++) {
      float4 hv = *(const float4*)(H + r*64 + fq*4);
      a += w[fq].x*hv.x + w[fq].y*hv.y + w[fq].z*hv.z + w[fq].w*hv.w;
    }
    float v = (a - bnm[d]) * bscale + bnb[d];
    VP[(r>>3)*512 + d*8 + (r&7)] = f2bf(v);
    HP[(r>>3)*512 + d*8 + (r&7)] = f2bf(H[r*64 + d]);
  }
}

// ---------------------------------------------------------------------------
// pass 1 (lean): per-column sums of exp2(s*M). No LDS, no barrier.
// ---------------------------------------------------------------------------
__global__ __launch_bounds__(256) void pass1_kernel(
    const float* __restrict__ M, const unsigned short* __restrict__ QP,
    const unsigned short* __restrict__ KP, float* __restrict__ pd)
{
  int tid = threadIdx.x;
  int wj = (blockIdx.x * blockDim.x + tid) >> 6;  // 0..8191
  int lane = tid & 63;
  int l31 = lane & 31, h = lane >> 5;
  int jb = wj & 255, slice = wj >> 8;             // 256 jb x 32 slices
  int j = jb*32 + l31;

  short8 kb[4];
  for (int m = 0; m < 4; m++)
    kb[m] = *(const short8*)(KP + (2*m + h)*65536 + j*8);

  float Mv[16];
  {
    int i0 = slice*8*32;
#pragma unroll
    for (int r = 0; r < 16; r++) {
      int ir = (r&3) + 8*(r>>2) + 4*h;
      Mv[r] = __builtin_nontemporal_load(M + (size_t)(i0 + ir)*NN + j);
    }
  }

  float d0 = 0.f, d1 = 0.f, d2 = 0.f, d3 = 0.f;
  for (int t = 0; t < 8; t++) {
    int i0 = (slice*8 + t) * 32;
    float Mn[16];
    if (t < 7) {
      int i1 = i0 + 32;
#pragma unroll
      for (int r = 0; r < 16; r++) {
        int ir = (r&3) + 8*(r>>2) + 4*h;
        Mn[r] = __builtin_nontemporal_load(M + (size_t)(i1 + ir)*NN + j);
      }
    }

    f32x16 acc;
    for (int r = 0; r < 16; r++) acc[r] = 0.f;
    for (int m = 0; m < 4; m++) {
      short8 qa = *(const short8*)(QP + (2*m + h)*65536 + (size_t)(i0 + l31)*8);
      acc = __builtin_amdgcn_mfma_f32_32x32x16_bf16(qa, kb[m], acc, 0, 0, 0);
    }

    d0 += fexp2(acc[0]*Mv[0]) + fexp2(acc[4]*Mv[4]) + fexp2(acc[8]*Mv[8])   + fexp2(acc[12]*Mv[12]);
    d1 += fexp2(acc[1]*Mv[1]) + fexp2(acc[5]*Mv[5]) + fexp2(acc[9]*Mv[9])   + fexp2(acc[13]*Mv[13]);
    d2 += fexp2(acc[2]*Mv[2]) + fexp2(acc[6]*Mv[6]) + fexp2(acc[10]*Mv[10]) + fexp2(acc[14]*Mv[14]);
    d3 += fexp2(acc[3]*Mv[3]) + fexp2(acc[7]*Mv[7]) + fexp2(acc[11]*Mv[11]) + fexp2(acc[15]*Mv[15]);

    if (t < 7) {
#pragma unroll
      for (int r = 0; r < 16; r++) Mv[r] = Mn[r];
    }
  }
  float drun = (d0 + d1) + (d2 + d3);
  drun += __shfl_xor(drun, 32);
  if (lane < 32) pd[(size_t)slice*NN + j] = drun;
}

// ---------------------------------------------------------------------------
// combine: cc[j] = log2(10 * D_j)
// ---------------------------------------------------------------------------
__global__ __launch_bounds__(256) void combine_kernel(
    const float* __restrict__ pd, float* __restrict__ colcc)
{
  int j = blockIdx.x * blockDim.x + threadIdx.x;
  float Dv = 0.f;
  for (int s = 0; s < 32; s++) Dv += pd[(size_t)s*NN + j];
  colcc[j] = log2f(Dv * 10.f);
}

// ---------------------------------------------------------------------------
// pass 2 (T14 write-late): per tm -- [issue stage loads] -> compute 2 ti
// blocks -> [ds_write staged tile] -> barrier. KP frags prefetched 1-deep
// across ti; V/H + Mv reads issued early in the ti body.
// Grid = 128 iblk x 8 slices; WG = 4 waves (iq = wid&1, dh = wid>>1).
// ---------------------------------------------------------------------------
#define MST 66   // 64 + 2 pad floats

__global__ __launch_bounds__(256) void pass2_kernel(
    const float* __restrict__ M, const unsigned short* __restrict__ QP,
    const unsigned short* __restrict__ KP, const unsigned short* __restrict__ VP,
    const unsigned short* __restrict__ HP, const float* __restrict__ colcc,
    float* __restrict__ opart)
{
  __shared__ __align__(16) float mt[2][64*MST];
  __shared__ __align__(16) float cls[1024];

  int iblk = blockIdx.x >> 3, slice = blockIdx.x & 7;
  int i0 = iblk * 64;
  int tid = threadIdx.x;
  int lane = tid & 63, wid = tid >> 6;
  int l31 = lane & 31, h = lane >> 5;
  int iq = wid & 1, dh = wid >> 1;
  int row = iq*32 + l31;
  int i_g = i0 + row;

  short8 qb[4];
  for (int m = 0; m < 4; m++)
    qb[m] = *(const short8*)(QP + (2*m + h)*65536 + (size_t)i_g*8);

#pragma unroll
  for (int k = 0; k < 4; k++)
    cls[tid + k*256] = colcc[slice*1024 + k*256 + tid];

  // staging map: idx = q*256 + tid -> row q*16 + (tid>>4), col (tid&15)*4
  const float* msrc = M + (size_t)i0*NN + slice*1024;
  int sr = tid >> 4, sc = (tid & 15) * 4;

  // prologue: stage tile 0 (blocking, one-time)
#pragma unroll
  for (int q = 0; q < 4; q++) {
    int r = q*16 + sr;
    f32x4 v = ntload4(msrc + (size_t)r*NN + sc);
    float* dst = &mt[0][r*MST + sc];
    *(float2*)(dst)     = make_float2(v.x, v.y);
    *(float2*)(dst + 2) = make_float2(v.z, v.w);
  }
  __syncthreads();

  f32x16 oacc;
  for (int r = 0; r < 16; r++) oacc[r] = 0.f;

  // KP prefetch for (tm=0, ti=0)
  short8 kcur[4];
  for (int m = 0; m < 4; m++)
    kcur[m] = *(const short8*)(KP + (2*m + h)*65536 + (size_t)(slice*1024 + l31)*8);

  for (int tm = 0; tm < 16; tm++) {
    // ---- issue stage loads for tile tm+1 (write-late) ----
    f32x4 sv[4];
    if (tm < 15) {
      const float* src = msrc + (tm+1)*64;
#pragma unroll
      for (int q = 0; q < 4; q++) {
        int r = q*16 + sr;
        sv[q] = ntload4(src + (size_t)r*NN + sc);
      }
    }
    const float* mb = mt[tm & 1];

#pragma unroll
    for (int ti = 0; ti < 2; ti++) {
      int jloc = tm*64 + ti*32;
      int jt = slice*1024 + jloc;

      // ---- prefetch next ti's KP frags (clamped reload at the very end) ----
      short8 knxt[4];
      {
        int jn = (jloc + 32 < 1024) ? (jt + 32) : jt;
#pragma unroll
        for (int m = 0; m < 4; m++)
          knxt[m] = *(const short8*)(KP + (2*m + h)*65536 + (size_t)(jn + l31)*8);
      }

      // ---- V/H B-frags: issue early (land under sacc/exp chain) ----
      int j8 = jt >> 3;
      const unsigned short* vbase = VP + (size_t)j8*512 + (dh*32 + l31)*8;
      const unsigned short* hbase = HP + (size_t)j8*512 + (dh*32 + l31)*8;
      short8 vb1 = *(const short8*)(vbase + h*512);
      short8 vb2 = *(const short8*)(vbase + (2 + h)*512);
      short8 hb1 = *(const short8*)(hbase + h*512);
      short8 hb2 = *(const short8*)(hbase + (2 + h)*512);

      // ---- Mv from LDS: 8 x b64, issue early too ----
      float2 mv2[8];
#pragma unroll
      for (int q = 0; q < 4; q++) {
        const float* rb = &mb[row*MST + ti*32 + 8*q + 4*h];
        mv2[2*q]   = *(const float2*)(rb);
        mv2[2*q+1] = *(const float2*)(rb + 2);
      }

      // ---- sacc = K x (Q*QSCALE)^T (lane = i, regs = j) ----
      f32x16 sacc;
      for (int r = 0; r < 16; r++) sacc[r] = 0.f;
      for (int m = 0; m < 4; m++)
        sacc = __builtin_amdgcn_mfma_f32_32x32x16_bf16(kcur[m], qb[m], sacc, 0, 0, 0);

      // ---- p = exp2(s*M - cc) (f32 M) ----
      float p[16];
#pragma unroll
      for (int q = 0; q < 4; q++) {
        float4 cc = *(const float4*)(&cls[jloc + 8*q + 4*h]);
        p[4*q+0] = fexp2(fmaf(sacc[4*q+0], mv2[2*q].x,   -cc.x));
        p[4*q+1] = fexp2(fmaf(sacc[4*q+1], mv2[2*q].y,   -cc.y));
        p[4*q+2] = fexp2(fmaf(sacc[4*q+2], mv2[2*q+1].x, -cc.z));
        p[4*q+3] = fexp2(fmaf(sacc[4*q+3], mv2[2*q+1].y, -cc.w));
      }

      // ---- pack P and M to bf16 words ----
      unsigned pu[8], mw[8];
#pragma unroll
      for (int k = 0; k < 8; k++) pu[k] = cvtpk(p[2*k], p[2*k+1]);
#pragma unroll
      for (int k = 0; k < 8; k++) mw[k] = cvtpk(mv2[k].x, mv2[k].y);

      // ---- half-swaps -> A-frag words ----
      asm volatile("v_permlane32_swap_b32 %0, %1" : "+v"(pu[0]), "+v"(pu[2]));
      asm volatile("v_permlane32_swap_b32 %0, %1" : "+v"(pu[1]), "+v"(pu[3]));
      asm volatile("v_permlane32_swap_b32 %0, %1" : "+v"(pu[4]), "+v"(pu[6]));
      asm volatile("v_permlane32_swap_b32 %0, %1" : "+v"(pu[5]), "+v"(pu[7]));
      asm volatile("v_permlane32_swap_b32 %0, %1" : "+v"(mw[0]), "+v"(mw[2]));
      asm volatile("v_permlane32_swap_b32 %0, %1" : "+v"(mw[1]), "+v"(mw[3]));
      asm volatile("v_permlane32_swap_b32 %0, %1" : "+v"(mw[4]), "+v"(mw[6]));
      asm volatile("v_permlane32_swap_b32 %0, %1" : "+v"(mw[5]), "+v"(mw[7]));

      W4 PA0, PA1, MA0, MA1;
      PA0.u[0] = pu[0]; PA0.u[1] = pu[1]; PA0.u[2] = pu[2]; PA0.u[3] = pu[3];
      PA1.u[0] = pu[4]; PA1.u[1] = pu[5]; PA1.u[2] = pu[6]; PA1.u[3] = pu[7];
      MA0.u[0] = mw[0]; MA0.u[1] = mw[1]; MA0.u[2] = mw[2]; MA0.u[3] = mw[3];
      MA1.u[0] = mw[4]; MA1.u[1] = mw[5]; MA1.u[2] = mw[6]; MA1.u[3] = mw[7];

      oacc = __builtin_amdgcn_mfma_f32_32x32x16_bf16(PA0.v, vb1, oacc, 0, 0, 0);
      oacc = __builtin_amdgcn_mfma_f32_32x32x16_bf16(PA1.v, vb2, oacc, 0, 0, 0);
      oacc = __builtin_amdgcn_mfma_f32_32x32x16_bf16(MA0.v, hb1, oacc, 0, 0, 0);
      oacc = __builtin_amdgcn_mfma_f32_32x32x16_bf16(MA1.v, hb2, oacc, 0, 0, 0);

#pragma unroll
      for (int m = 0; m < 4; m++) kcur[m] = knxt[m];
    }

    // ---- write-late: staged tile lands AFTER compute ----
    if (tm < 15) {
      float* dstb = mt[(tm+1) & 1];
#pragma unroll
      for (int q = 0; q < 4; q++) {
        int r = q*16 + sr;
        float* dst = &dstb[r*MST + sc];
        *(float2*)(dst)     = make_float2(sv[q].x, sv[q].y);
        *(float2*)(dst + 2) = make_float2(sv[q].z, sv[q].w);
      }
    }
    __syncthreads();
  }

  float* obase = opart + (size_t)slice*OSZ;
#pragma unroll
  for (int r = 0; r < 16; r++) {
    int orow = i0 + iq*32 + (r&3) + 8*(r>>2) + 4*h;
    int ocol = dh*32 + l31;
    obase[(size_t)orow*64 + ocol] = oacc[r];
  }
}

// ---------------------------------------------------------------------------
// reduce: out = sum over NSL slices of opart  (float4, fully coalesced)
// ---------------------------------------------------------------------------
__global__ __launch_bounds__(256) void reduce_kernel(
    const float* __restrict__ opart, float* __restrict__ out)
{
  int e4 = blockIdx.x * blockDim.x + threadIdx.x;   // 0..131071
  const float4* p = (const float4*)opart;
  float4 a = p[e4];
#pragma unroll
  for (int s = 1; s < NSL; s++) {
    float4 b = p[(size_t)s*(OSZ/4) + e4];
    a.x += b.x; a.y += b.y; a.z += b.z; a.w += b.w;
  }
  ((float4*)out)[e4] = a;
}

// ---------------------------------------------------------------------------
extern "C" void kernel_launch(void* const* d_in, const int* in_sizes, int n_in,
                              void* d_out, int out_size, void* d_ws, size_t ws_size,
                              hipStream_t stream) {
  const float* X   = (const float*)d_in[0];
  const float* H   = (const float*)d_in[1];
  const float* M   = (const float*)d_in[2];
  const float* Qw  = (const float*)d_in[3];
  const float* Qb  = (const float*)d_in[4];
  const float* Kw  = (const float*)d_in[5];
  const float* Kb  = (const float*)d_in[6];
  const float* Vw  = (const float*)d_in[7];
  const float* Vb  = (const float*)d_in[8];
  const float* bng = (const float*)d_in[9];
  const float* bnb = (const float*)d_in[10];
  const float* bnm = (const float*)d_in[11];
  const float* bnv = (const float*)d_in[12];
  float* out = (float*)d_out;

  char* ws = (char*)d_ws;
  const size_t MB = 1024*1024;
  unsigned short* QP  = (unsigned short*)(ws);           // 1 MB
  unsigned short* KP  = (unsigned short*)(ws + 1*MB);
  unsigned short* VP  = (unsigned short*)(ws + 2*MB);
  unsigned short* HP  = (unsigned short*)(ws + 3*MB);
  float* pd           = (float*)(ws + 4*MB);             // 1 MB
  float* colcc        = (float*)(ws + 5*MB);             // 32 KB
  float* opart        = (float*)(ws + 6*MB);             // 16 MB

  qkv_kernel<<<512, 256, 0, stream>>>(X, H, Qw, Qb, Kw, Kb, Vw, Vb,
                                      bng, bnb, bnm, bnv, QP, KP, VP, HP);
  pass1_kernel<<<2048, 256, 0, stream>>>(M, QP, KP, pd);
  combine_kernel<<<32, 256, 0, stream>>>(pd, colcc);
  pass2_kernel<<<1024, 256, 0, stream>>>(M, QP, KP, VP, HP, colcc, opart);
  reduce_kernel<<<512, 256, 0, stream>>>(opart, out);
}